// Round 6
// baseline (104.660 us; speedup 1.0000x reference)
//
#include <hip/hip_runtime.h>

#define EPS 1e-12f

constexpr int D       = 1024;  // feature dim
constexpr int K       = 16;    // centers per class
constexpr int NS      = 16;    // index-range slices per class
constexpr int BATCH   = 16;    // samples per epilogue batch
constexpr int LISTCAP = 512;   // LDS match-list capacity (= SLICE, worst case)

// ---------------------------------------------------------------------------
// Fused main kernel. Block (c, s) = (bid % C, bid / C):
//   phase 1: scan labels[s*SLICE .. +SLICE), build deterministic LDS list of
//            matching sample indices (shfl_up wave scan + cross-wave prefix).
//   phase 2: 4 waves hold the 16 center rows of class c in registers
//            (4 float4-fragments per row per lane), compute norms, then loop
//            the matched samples with 1-deep x prefetch; per-batch epilogue.
//   tail: one atomicAdd of the block's pre-scaled sum into out (out was
//         zeroed by a 4-byte memset node preceding this kernel).
// ---------------------------------------------------------------------------
__global__ __launch_bounds__(256) void cosine_loss_fused(
    const float* __restrict__ x, const int* __restrict__ labels,
    const float* __restrict__ centers, float* __restrict__ out,
    int B, int C, float inv_B) {
    const int bid  = blockIdx.x;
    const int c    = bid % C;
    const int sl   = bid / C;
    const int tid  = threadIdx.x;
    const int w    = tid >> 6;
    const int lane = tid & 63;

    __shared__ int   list[LISTCAP];
    __shared__ int   wsum[4];
    __shared__ float dotsLDS[BATCH][K + 1];   // +1 pad vs bank conflicts
    __shared__ float xxLDS[BATCH];
    __shared__ float cinvLDS[K];
    __shared__ float accLDS;

    const int SLICE = (B + NS - 1) / NS;
    const int base  = sl * SLICE;
    const int lim   = min(SLICE, B - base);          // valid labels in slice
    const int rpt   = (SLICE + 255) >> 8;            // loads per thread

    // ---- phase 1a: per-thread match mask over the slice (coalesced) ----
    int mmask = 0, cnt_t = 0;
    for (int r = 0; r < rpt; ++r) {
        const int idx = r * 256 + tid;
        if (idx < lim && labels[base + idx] == c) { mmask |= 1 << r; ++cnt_t; }
    }

    // ---- phase 1b: intra-wave inclusive scan + cross-wave prefix ----
    int v = cnt_t;
#pragma unroll
    for (int off = 1; off < 64; off <<= 1) {
        const int u = __shfl_up(v, off, 64);
        if (lane >= off) v += u;
    }
    if (lane == 63) wsum[w] = v;
    __syncthreads();
    int prefix = 0;
#pragma unroll
    for (int ww = 0; ww < 4; ++ww) if (ww < w) prefix += wsum[ww];
    const int cnt = wsum[0] + wsum[1] + wsum[2] + wsum[3];

    // ---- phase 1c: place matching indices (deterministic order) ----
    int pos = prefix + v - cnt_t;
    for (int r = 0; r < rpt; ++r) {
        if ((mmask >> r) & 1) list[pos++] = base + r * 256 + tid;
    }
    if (tid == 0) accLDS = 0.0f;
    __syncthreads();

    // ---- phase 2a: preload this wave's 4 center rows, compute norms ----
    const int kbase = 4 * w;
    float4 cf[4][4];
    float  cc[4] = {0.f, 0.f, 0.f, 0.f};
#pragma unroll
    for (int kk = 0; kk < 4; ++kk) {
        const float* crow = centers + (size_t)(c * K + kbase + kk) * D;
#pragma unroll
        for (int j = 0; j < 4; ++j) {
            float4 t = *reinterpret_cast<const float4*>(crow + j * 256 + lane * 4);
            cf[kk][j] = t;
            cc[kk] += t.x * t.x + t.y * t.y + t.z * t.z + t.w * t.w;
        }
    }
#pragma unroll
    for (int off = 32; off >= 1; off >>= 1) {
#pragma unroll
        for (int kk = 0; kk < 4; ++kk) cc[kk] += __shfl_xor(cc[kk], off, 64);
    }
    if (lane == 0) {
#pragma unroll
        for (int kk = 0; kk < 4; ++kk)
            cinvLDS[kbase + kk] = 1.0f / sqrtf(cc[kk] + EPS);
    }

    // ---- phase 2b: sample loop, 1-deep x prefetch, per-batch epilogue ----
    float4 xf[4], xfn[4];
    if (cnt > 0) {
        const float* xrow = x + (size_t)list[0] * D;
#pragma unroll
        for (int j = 0; j < 4; ++j)
            xf[j] = *reinterpret_cast<const float4*>(xrow + j * 256 + lane * 4);
    }
    for (int si = 0; si < cnt; ++si) {
        if (si + 1 < cnt) {
            const float* xrow = x + (size_t)list[si + 1] * D;
#pragma unroll
            for (int j = 0; j < 4; ++j)
                xfn[j] = *reinterpret_cast<const float4*>(xrow + j * 256 + lane * 4);
        }
        float acc[4] = {0.f, 0.f, 0.f, 0.f};
        float xx = 0.f;
#pragma unroll
        for (int j = 0; j < 4; ++j) {
#pragma unroll
            for (int kk = 0; kk < 4; ++kk) {
                acc[kk] += cf[kk][j].x * xf[j].x + cf[kk][j].y * xf[j].y +
                           cf[kk][j].z * xf[j].z + cf[kk][j].w * xf[j].w;
            }
            if (w == 0)
                xx += xf[j].x * xf[j].x + xf[j].y * xf[j].y +
                      xf[j].z * xf[j].z + xf[j].w * xf[j].w;
        }
#pragma unroll
        for (int off = 32; off >= 1; off >>= 1) {
#pragma unroll
            for (int kk = 0; kk < 4; ++kk) acc[kk] += __shfl_xor(acc[kk], off, 64);
            if (w == 0) xx += __shfl_xor(xx, off, 64);
        }
        const int slot = si & (BATCH - 1);
        if (lane == 0) {
#pragma unroll
            for (int kk = 0; kk < 4; ++kk) dotsLDS[slot][kbase + kk] = acc[kk];
            if (w == 0) xxLDS[slot] = xx;
        }
#pragma unroll
        for (int j = 0; j < 4; ++j) xf[j] = xfn[j];

        // batch epilogue when batch full or last sample
        if (slot == BATCH - 1 || si + 1 == cnt) {
            __syncthreads();
            const int bl = slot + 1;   // samples in this batch
            if (tid < 64) {
                float per = 0.f;
                if (tid < bl) {
                    const float nxinv = 1.0f / sqrtf(xxLDS[tid] + EPS);
                    float sum_d = 0.f, sum_d2 = 0.f;
#pragma unroll
                    for (int k = 0; k < K; ++k) {
                        const float dk = 1.0f - dotsLDS[tid][k] * nxinv * cinvLDS[k];
                        sum_d  += dk;
                        sum_d2 += dk * dk;
                    }
                    per = sum_d - sum_d2 / sum_d;
                }
#pragma unroll
                for (int off = 32; off >= 1; off >>= 1)
                    per += __shfl_xor(per, off, 64);
                if (tid == 0) accLDS += per;
            }
            __syncthreads();
        }
    }

    __syncthreads();
    if (tid == 0 && cnt > 0) atomicAdd(out, accLDS * inv_B);
}

// ---------------------------------------------------------------------------
extern "C" void kernel_launch(void* const* d_in, const int* in_sizes, int n_in,
                              void* d_out, int out_size, void* d_ws, size_t ws_size,
                              hipStream_t stream) {
    const float* x       = (const float*)d_in[0];
    const int*   labels  = (const int*)d_in[1];
    const float* centers = (const float*)d_in[2];

    const int B = in_sizes[1];              // 8192
    const int C = in_sizes[2] / (K * D);    // 90
    const int nblocks = C * NS;             // 1440

    float* out = (float*)d_out;

    // Zero the (poisoned) scalar output; graph-capturable memset node.
    hipMemsetAsync(out, 0, sizeof(float), stream);

    cosine_loss_fused<<<nblocks, 256, 0, stream>>>(
        x, labels, centers, out, B, C, 1.0f / (float)B);
}